// Round 13
// baseline (93.726 us; speedup 1.0000x reference)
//
#include <hip/hip_runtime.h>

// B=128, K=256, M=8, D=128 ; rows = B*K = 32768 flattened (b,k)
// r8:  compact positive rows -> ~half the work.             [93.7us]
// r12: 64 rows/block, A shared over 2 rf, 32x32 MFMA, LDS.  [93.6us best]
// r13: DELETE the LDS middleman: A-fragments load straight Pw->VGPR
//      (coalesced 1KB wave-loads, chunk-ahead double buffer), Pw
//      replicated 8x XCD-local. No GLD16 / ds_read / lgkmcnt trips.
#define LT      20.0f
#define LN2     0.69314718055994531f
#define C2EXP   28.853900817779268f   // LT/ln2 : e^(LT*x) = 2^(C2EXP*x)
#define CHUNKS  16                    // 16 chunks x 128 prototype-cols
#define NBLK    512                   // worst case ceil(32768/64)
#define PW_COPY 262144                // halves per Pw copy (512 KB)

typedef _Float16 half8  __attribute__((ext_vector_type(8)));
typedef float    f32x16 __attribute__((ext_vector_type(16)));

#if __has_builtin(__builtin_amdgcn_exp2f)
#define EXP2F(x) __builtin_amdgcn_exp2f(x)
#else
#define EXP2F(x) __expf(0.69314718055994531f * (x))
#endif

// ---------------- layout (32x32x16_f16), HW-verified in r10/r11/r12 ------
// C/D: col = lane&31 (V-row), row m = (reg&3) + 8*(reg>>2) + 4*(lane>>5)
// A: lane holds A-row (lane&31), k = (lane>>5)*8 + j
// A-row permutation: concept c_loc, proto p -> A-row
//   a = (p&3) | ((c_loc&1)<<2) | ((c_loc>>1)<<3) | ((p>>2)<<4)
// => lane (hi=lane>>5) accumulates 2 COMPLETE concepts:
//   c_loc=hi  : regs {0..3, 8..11} ; c_loc=hi+2 : regs {4..7, 12..15}
// Pw slot id = ch*2048 + (g*8 + s)*64 + lane (half8 each)
// Main lane reads slot (ch, g, s, lane): one coalesced 1KB load per (ch,s).

// ---- prep (blocks 0..255: 8 XCD-local copies) + compact (block 256) ----
// Prep block b dispatches to XCD b%8 (round-robin) and writes copy b&7:
// each copy is PRODUCED in the L2 that main blocks with blockIdx%8==b&7
// consume. Portion p = b>>3 covers slots [p*1024, +1024).
__global__ __launch_bounds__(1024)
void mpcl_prep_compact(const float* __restrict__ P,
                       const int*   __restrict__ labels,
                       _Float16* __restrict__ Pw,
                       int* __restrict__ ridx, int* __restrict__ npos)
{
    __shared__ int wcnt[512];
    __shared__ int wsum[8];
    __shared__ int sbase[512];
    __shared__ int tot;

    if (blockIdx.x < 256) {
        int copy = blockIdx.x & 7;
        int t    = (blockIdx.x >> 3) * 1024 + threadIdx.x;   // 0..32767
        int gcol = t >> 4;                            // concept*8+proto col
        int dblk = t & 15;                            // d/8
        const float* src = P + ((size_t)gcol << 7) + dblk * 8;
        float4 x0 = *(const float4*)src;
        float4 x1 = *(const float4*)(src + 4);

        int ch = gcol >> 7, col = gcol & 127;
        int g  = col >> 5,  col5 = col & 31;
        int cl = col5 >> 3, p = col5 & 7;             // concept-local, proto
        int a  = (p & 3) | ((cl & 1) << 2) | ((cl >> 1) << 3) | ((p >> 2) << 4);
        int hi = dblk & 1, s = dblk >> 1;
        int l  = (hi << 5) | a;
        int slot = ch * 2048 + (g * 8 + s) * 64 + l;

        half8 hv;   // pre-scaled: MFMA emits y = C2EXP * sim directly
        hv[0] = (_Float16)(C2EXP * x0.x); hv[1] = (_Float16)(C2EXP * x0.y);
        hv[2] = (_Float16)(C2EXP * x0.z); hv[3] = (_Float16)(C2EXP * x0.w);
        hv[4] = (_Float16)(C2EXP * x1.x); hv[5] = (_Float16)(C2EXP * x1.y);
        hv[6] = (_Float16)(C2EXP * x1.z); hv[7] = (_Float16)(C2EXP * x1.w);
        *(half8*)(Pw + (size_t)copy * PW_COPY + (size_t)slot * 8) = hv;
    } else {
        // ---- compact (r8-verbatim): ordered list of label==1 rows ----
        const int tid = threadIdx.x, lane = tid & 63, w = tid >> 6;
        int lab[32];
#pragma unroll
        for (int i = 0; i < 32; ++i) lab[i] = labels[i * 1024 + tid];
#pragma unroll
        for (int i = 0; i < 32; ++i) {
            unsigned long long m = __ballot(lab[i] == 1);
            if (lane == 0) wcnt[i * 16 + w] = __popcll(m);
        }
        __syncthreads();

        int v = 0, orig = 0;
        if (tid < 512) { v = wcnt[tid]; orig = v; }
#pragma unroll
        for (int off = 1; off < 64; off <<= 1) {      // intra-wave scan
            int t2 = __shfl_up(v, off);
            if (lane >= off) v += t2;
        }
        if (lane == 63 && w < 8) wsum[w] = v;
        __syncthreads();
        if (tid == 0) {
            int acc = 0;
#pragma unroll
            for (int i = 0; i < 8; ++i) { int t2 = wsum[i]; wsum[i] = acc; acc += t2; }
            tot = acc; npos[0] = acc;
        }
        __syncthreads();
        if (tid < 512) sbase[tid] = v - orig + wsum[w];
        __syncthreads();

#pragma unroll
        for (int i = 0; i < 32; ++i) {                // ordered scatter
            unsigned long long m = __ballot(lab[i] == 1);
            int pos = sbase[i * 16 + w] + __popcll(m & ((1ull << lane) - 1));
            if (lab[i] == 1) ridx[pos] = i * 1024 + tid;
        }
        for (int j = tot + tid; j < 32768; j += 1024) ridx[j] = 0;   // pad
    }
}

// Grid: 512 blocks x 512 thr (8 waves); ~257 active (1/CU, 2 waves/SIMD).
// Block owns 64 COMPACTED rows (2 rf x 32) x all 2048 cols.
// wave w: g=w&3 (concept group), kh=w>>2 (chunks kh*8..kh*8+7).
// REGISTER-DIRECT: per chunk, 8 coalesced 1KB wave-loads (Pw->VGPR, from
// the XCD-LOCAL copy) double-buffered one chunk ahead; 16 MFMA (A shared
// across 2 rf); 4 in-lane SOFT8. No LDS, no barriers, no DMA trips in the
// K-loop. waves_per_eu(2,2) -> 256-VGPR budget for the ~180-reg live set
// (WRITE_SIZE is the spill tripwire).
__global__ __attribute__((amdgpu_flat_work_group_size(512, 512),
                          amdgpu_waves_per_eu(2, 2)))
void mpcl_main(const float* __restrict__ V,        // (32768, 128) f32
               const _Float16* __restrict__ Pw,    // packed P, 8 copies
               const int* __restrict__ ridx,       // compacted rows
               const int* __restrict__ npos,
               float* __restrict__ part)           // (NBLK, 2) partials
{
    __shared__ float sh_denom[64];
    __shared__ float sh_simpos[64];

    const int np = *npos;
    const int rowbase = blockIdx.x * 64;
    if (rowbase >= np) return;                    // uniform early exit

    const int tid = threadIdx.x;
    const int l   = tid & 63;
    const int w   = tid >> 6;       // 0..7
    const int g   = w & 3;          // concept group in chunk
    const int kh  = w >> 2;         // chunk half: chunks kh*8 .. kh*8+7
    const int a   = l & 31;         // V-row slot AND A-row index
    const int hi  = l >> 5;

    if (tid < 64) { sh_denom[tid] = 0.0f; sh_simpos[tid] = 0.0f; }

    // ---- 2 row-fragments: rows rowbase + rf*32 + a ----
    int myrow[2], rowk[2];
    half8 vh[2][8];
#pragma unroll
    for (int rf = 0; rf < 2; ++rf) {
        int pos = rowbase + rf * 32 + a;
        myrow[rf] = ridx[pos < np ? pos : np - 1];   // clamped gather
        rowk[rf]  = myrow[rf] & 255;
        const float* vr = V + ((size_t)myrow[rf] << 7) + hi * 8;
#pragma unroll
        for (int s = 0; s < 8; ++s) {
            float4 x0 = *(const float4*)(vr + s * 16);
            float4 x1 = *(const float4*)(vr + s * 16 + 4);
            vh[rf][s][0] = (_Float16)x0.x; vh[rf][s][1] = (_Float16)x0.y;
            vh[rf][s][2] = (_Float16)x0.z; vh[rf][s][3] = (_Float16)x0.w;
            vh[rf][s][4] = (_Float16)x1.x; vh[rf][s][5] = (_Float16)x1.y;
            vh[rf][s][6] = (_Float16)x1.z; vh[rf][s][7] = (_Float16)x1.w;
        }
    }
    __syncthreads();   // sh_* init visible (only barrier before the fold)

    // XCD-local copy: main block b runs on XCD b%8, reads copy b&7.
    // lane's fragment (ch, s): pw[ch*2048 + s*64]
    const half8* pw = (const half8*)(Pw + (size_t)(blockIdx.x & 7) * PW_COPY)
                    + (size_t)g * 512 + l;

#define LOADCH(CH, BUF) do {                                   \
    _Pragma("unroll")                                          \
    for (int s = 0; s < 8; ++s)                                \
        BUF[s] = pw[(size_t)(CH) * 2048 + s * 64];             \
} while (0)

#define SOFT8(y0,y1,y2,y3,y4,y5,y6,y7, CONCEPT, DN, SLOT) do {              \
    float e0=EXP2F(y0), e1=EXP2F(y1), e2=EXP2F(y2), e3=EXP2F(y3);           \
    float e4=EXP2F(y4), e5=EXP2F(y5), e6=EXP2F(y6), e7=EXP2F(y7);           \
    float es = ((e0+e1)+(e2+e3)) + ((e4+e5)+(e6+e7));                       \
    float ss = fmaf(e0,y0, fmaf(e1,y1, fmaf(e2,y2, e3*y3)))                 \
             + fmaf(e4,y4, fmaf(e5,y5, fmaf(e6,y6, e7*y7)));                \
    float simY = __fdividef(ss, es);            /* = C2EXP * sim_c */       \
    DN += EXP2F(simY);                                                      \
    if ((CONCEPT) == rowk[(SLOT) >> 5]) sh_simpos[SLOT] = simY;             \
} while (0)

#define COMPUTE(BUF, CH) do {                                               \
    f32x16 ac0 = {0.f,0.f,0.f,0.f,0.f,0.f,0.f,0.f,0.f,0.f,0.f,0.f,0.f,0.f,0.f,0.f}; \
    f32x16 ac1 = {0.f,0.f,0.f,0.f,0.f,0.f,0.f,0.f,0.f,0.f,0.f,0.f,0.f,0.f,0.f,0.f}; \
    _Pragma("unroll")                                                       \
    for (int s = 0; s < 8; ++s) {                                           \
        ac0 = __builtin_amdgcn_mfma_f32_32x32x16_f16(BUF[s], vh[0][s], ac0, 0, 0, 0); \
        ac1 = __builtin_amdgcn_mfma_f32_32x32x16_f16(BUF[s], vh[1][s], ac1, 0, 0, 0); \
    }                                                                       \
    const int cb = ((CH) << 4) + (g << 2) + hi;   /* concept 16ch+4g+hi */  \
    SOFT8(ac0[0], ac0[1], ac0[2],  ac0[3],  ac0[8],  ac0[9],  ac0[10], ac0[11], cb,     dn0, a); \
    SOFT8(ac0[4], ac0[5], ac0[6],  ac0[7],  ac0[12], ac0[13], ac0[14], ac0[15], cb + 2, dn0, a); \
    SOFT8(ac1[0], ac1[1], ac1[2],  ac1[3],  ac1[8],  ac1[9],  ac1[10], ac1[11], cb,     dn1, 32 + a); \
    SOFT8(ac1[4], ac1[5], ac1[6],  ac1[7],  ac1[12], ac1[13], ac1[14], ac1[15], cb + 2, dn1, 32 + a); \
} while (0)

    float dn0 = 0.f, dn1 = 0.f;
    const int ch0 = kh * 8;

    half8 pA[8], pB[8];
    LOADCH(ch0, pA);                               // chunk ch0 in flight

#pragma unroll 1
    for (int i = 0; i < 8; i += 2) {
        LOADCH(ch0 + i + 1, pB);                   // issue next chunk's loads
        __builtin_amdgcn_sched_barrier(0);         // pin issue above compute
        COMPUTE(pA, ch0 + i);

        if (i + 2 < 8) LOADCH(ch0 + i + 2, pA);    // issue chunk i+2
        __builtin_amdgcn_sched_barrier(0);
        COMPUTE(pB, ch0 + i + 1);
    }

    // ---- fold dn per row: lanes l / l+32 share a row; 8 waves add ----
    {
        float t0 = dn0 + __shfl_xor(dn0, 32);
        float t1 = dn1 + __shfl_xor(dn1, 32);
        if (hi == 0) {
            atomicAdd(&sh_denom[a],      t0);
            atomicAdd(&sh_denom[32 + a], t1);
        }
    }
    __syncthreads();

    // ---- block loss over its <=64 compacted rows (all label==1) ----
    // lp = log(denom) - LT*(sim_pos + margin) = log(denom) - ln2*simY - 1.0
    if (w == 0) {
        float s = 0.f, cc = 0.f;
        if (rowbase + l < np) {
            s  = logf(sh_denom[l] + 1e-8f) - LN2 * sh_simpos[l] - 1.0f;
            cc = 1.0f;
        }
#pragma unroll
        for (int off = 32; off >= 1; off >>= 1) {
            s  += __shfl_down(s, off);
            cc += __shfl_down(cc, off);
        }
        if (l == 0) {                  // plain stores; finisher reduces
            part[2 * blockIdx.x]     = s;
            part[2 * blockIdx.x + 1] = cc;
        }
    }
}

// 1 block x 512 threads: reduce the active blocks' (s, cc) partials.
__global__ __launch_bounds__(512)
void mpcl_finish(const float* __restrict__ part, const int* __restrict__ npos,
                 float* __restrict__ out)
{
    __shared__ float sh[16];
    const int tid  = threadIdx.x;
    const int lane = tid & 63;
    const int w    = tid >> 6;
    const int nact = (*npos + 63) >> 6;           // active main blocks

    float s = 0.f, cc = 0.f;
    for (int i = tid; i < nact; i += 512) {
        s  += part[2 * i];
        cc += part[2 * i + 1];
    }
#pragma unroll
    for (int off = 32; off >= 1; off >>= 1) {
        s  += __shfl_down(s, off);
        cc += __shfl_down(cc, off);
    }
    if (lane == 0) { sh[w] = s; sh[8 + w] = cc; }
    __syncthreads();
    if (tid == 0) {
        float ts = 0.f, tc = 0.f;
#pragma unroll
        for (int i = 0; i < 8; ++i) { ts += sh[i]; tc += sh[8 + i]; }
        out[0] = (tc > 0.0f) ? (ts / tc) : ts;
    }
}

extern "C" void kernel_launch(void* const* d_in, const int* in_sizes, int n_in,
                              void* d_out, int out_size, void* d_ws, size_t ws_size,
                              hipStream_t stream)
{
    const float* V      = (const float*)d_in[0];
    const int*   labels = (const int*)d_in[1];
    const float* P      = (const float*)d_in[2];
    float* out = (float*)d_out;

    int*      npos = (int*)d_ws;                        // [0]
    float*    part = (float*)((char*)d_ws + 256);       // 512 x 2 floats
    int*      ridx = (int*)((char*)d_ws + 16384);       // 128 KB
    _Float16* Pw   = (_Float16*)((char*)d_ws + 147456); // 8 x 512 KB packed P

    mpcl_prep_compact<<<257, 1024, 0, stream>>>(P, labels, Pw, ridx, npos);
    mpcl_main<<<NBLK, 512, 0, stream>>>(V, Pw, ridx, npos, part);
    mpcl_finish<<<1, 512, 0, stream>>>(part, npos, out);
}